// Round 1
// baseline (247.319 us; speedup 1.0000x reference)
//
#include <hip/hip_runtime.h>
#include <hip/hip_fp8.h>

#define S_LEN 512
#define BATCH 256
#define L 128
#define PAD_ID 0
#define START_ID 1

typedef int    i32x8 __attribute__((ext_vector_type(8)));
typedef int    i32x4 __attribute__((ext_vector_type(4)));
typedef float  f32x4 __attribute__((ext_vector_type(4)));
typedef unsigned int   u32x4 __attribute__((ext_vector_type(4)));
typedef unsigned short u16x2 __attribute__((ext_vector_type(2)));

__device__ __forceinline__ unsigned int umax2(unsigned int a, unsigned int b) {
    u16x2 x = __builtin_bit_cast(u16x2, a), y = __builtin_bit_cast(u16x2, b);
#if defined(__has_builtin) && __has_builtin(__builtin_elementwise_max)
    return __builtin_bit_cast(unsigned int, __builtin_elementwise_max(x, y));  // v_pk_max_u16
#else
    u16x2 r; r.x = x.x > y.x ? x.x : y.x; r.y = x.y > y.y ? x.y : y.y;
    return __builtin_bit_cast(unsigned int, r);
#endif
}
__device__ __forceinline__ float frcp(float x) {
#if defined(__has_builtin) && __has_builtin(__builtin_amdgcn_rcpf)
    return __builtin_amdgcn_rcpf(x);
#else
    return 1.0f / x;
#endif
}
// NaN-killing sanitizer (fmaxf(NaN,lo)=lo on AMD): result always in [lo,hi], never NaN.
__device__ __forceinline__ float sane(float x, float lo, float hi) {
    return fminf(fmaxf(x, lo), hi);
}
__device__ __forceinline__ int pk2_fp8(float a, float b) {
#if defined(__has_builtin) && __has_builtin(__builtin_amdgcn_cvt_pk_fp8_f32)
    return __builtin_amdgcn_cvt_pk_fp8_f32(a, b, 0, false);
#else
    __hip_fp8_e4m3 A(a), B(b);
    return (int)A.__x | ((int)B.__x << 8);
#endif
}
// exact max byte (u8) over 8 dwords of positive-e4m3 bytes, via even/odd u16 lanes
__device__ __forceinline__ unsigned int bmax8(u32x4 a, u32x4 b) {
    const unsigned int M = 0x00FF00FFu;
    unsigned int l0 = umax2(a.x & M, a.y & M), l1 = umax2(a.z & M, a.w & M);
    unsigned int l2 = umax2(b.x & M, b.y & M), l3 = umax2(b.z & M, b.w & M);
    unsigned int h0 = umax2((a.x >> 8) & M, (a.y >> 8) & M);
    unsigned int h1 = umax2((a.z >> 8) & M, (a.w >> 8) & M);
    unsigned int h2 = umax2((b.x >> 8) & M, (b.y >> 8) & M);
    unsigned int h3 = umax2((b.z >> 8) & M, (b.w >> 8) & M);
    unsigned int v = umax2(umax2(umax2(l0, l1), umax2(l2, l3)),
                           umax2(umax2(h0, h1), umax2(h2, h3)));
    u16x2 t = __builtin_bit_cast(u16x2, v);
    return (unsigned int)(t.x > t.y ? t.x : t.y);
}
__device__ __forceinline__ float fp8dec(unsigned int bb) {   // e4m3 byte -> float
    bb &= 0x7Fu;
    int e = (int)(bb >> 3), mt = (int)(bb & 7u);
    float v = e ? __builtin_ldexpf((float)(8 + mt), e - 10)
                : __builtin_ldexpf((float)mt, -9);
    return sane(v, 1e-9f, 448.f);
}

// ws layout (unchanged): qf[256][128] fp8 | qb[256][128] fp8 | Sf[256] f32 | Sb[256] f32 | n[256] i32
#define WS_QF 0
#define WS_QB 32768
#define WS_SF 65536
#define WS_SB 66560
#define WS_N  67584

// prefix-ones length of row b, with byte/f32 mask-encoding self-detect (first 8KB scan).
__device__ __forceinline__ int compute_len(const void* masks, int b, int lane) {
    const unsigned int* mw0 = (const unsigned int*)masks;
    int pred = 0;
    #pragma unroll
    for (int k = 0; k < 32; ++k) {
        unsigned int w0 = mw0[lane + 64 * k];
        pred |= (w0 > 1u && w0 != 0x3f800000u);
    }
    const bool isbyte = (__ballot(pred) != 0ull);
    int cnt = 0;
    if (isbyte) {
        const unsigned int* mw = mw0 + b * (S_LEN / 4);
        #pragma unroll
        for (int k = 0; k < 2; ++k) {
            unsigned int w0 = mw[lane + 64 * k];
            cnt += ((w0 & 0xffu) != 0) + ((w0 & 0xff00u) != 0) +
                   ((w0 & 0xff0000u) != 0) + ((w0 & 0xff000000u) != 0);
        }
    } else {
        const unsigned int* mw = mw0 + b * S_LEN;
        #pragma unroll
        for (int k = 0; k < 8; ++k) cnt += (mw[lane + 64 * k] != 0u);
    }
    #pragma unroll
    for (int off = 32; off; off >>= 1) cnt += __shfl_xor(cnt, off, 64);
    return cnt;
}

// r13: ONE WAVE PER CHAIN, barrier-free step. A = expT chunk (16 distinct output
// rows x K=128), B = fp8 state (cols replicated). Key identity: the f8f6f4 byte
// swizzle k(s)=16*(s&7)+(s>>3) (s = 32*(lane>>4)+local, verified by r12's qs/LDBX
// layouts) makes each lane's D outputs {j=16t+4g+r} EXACTLY its next-step B-frag
// k-set. Each lane updates 2 outputs (cndmask-select from 8 D-frags by m), writes
// 2 bytes to a 128B wave-private LDS buffer at s(j)=8*(j&15)+(j>>4) (inverse of
// k()), reads back contiguous b128x2. Ordering = in-wave s_waitcnt lgkmcnt(0):
// no s_barrier, no vmcnt drain, emit prefetch (distance 4) stays in flight.
// Blocks 0..511: scan (b = bid&255, dir = bid>>8). Blocks 512..767: gold.
__global__ __launch_bounds__(64, 1) void k_scan(
        const float* __restrict__ emit, const int* __restrict__ labels,
        const void* __restrict__ masks, const float* __restrict__ T,
        unsigned char* __restrict__ ws, float* __restrict__ out) {
    const int bid  = blockIdx.x;
    const int lane = threadIdx.x;

    if (bid >= 2 * BATCH) {               // ---- gold (exact f32) ----
        const int b = bid - 2 * BATCH;
        const int len = compute_len(masks, b, lane);
        float gsum = 0.f;
        for (int tt = lane; tt < len; tt += 64) {
            int nxt = labels[b * S_LEN + tt];
            int prv = tt ? labels[b * S_LEN + tt - 1] : START_ID;
            gsum += emit[((size_t)tt * BATCH + b) * L + nxt] + T[prv * L + nxt];
            if (tt == len - 1) gsum += T[nxt * L + PAD_ID];
        }
        #pragma unroll
        for (int off = 32; off; off >>= 1) gsum += __shfl_xor(gsum, off, 64);
        if (lane == 0) atomicAdd(out, -gsum);
        return;
    }

    const int b   = bid & (BATCH - 1);
    const int dir = bid >> 8;             // 0 = forward, 1 = backward
    const int g = lane >> 4, m = lane & 15;

    const int len = compute_len(masks, b, lane);
    const int n  = len - 1;
    const int kf = n / 2;
    const int nB = n - kf - 1;
    const int steps = dir ? (nB > 0 ? nB : 0) : kf;
    if (dir == 1 && n < 1) return;        // inactive backward chain

    // per-lane output pair: j1 = 16*(m>>1) + 4g + 2*(m&1), j2 = j1+1
    const int tm = m >> 1;
    const int j1 = 16 * tm + 4 * g + 2 * (m & 1);
    const int s1 = 8 * (j1 & 15) + tm;    // LDS slot of j1; j2 -> s1+8

    __shared__ __align__(16) unsigned char st[128];   // fp8 state, swizzled order

    // ---- A-fragments: E rows in f8f6f4 swizzled layout (row = m, byte->k) ----
    // fwd: A_t[m][k] = exp(T[k][16t+m])   (y[j] = sum_i expT[i][j] q[i])
    // bwd: A_t[m][k] = exp(T[16t+m][k])   (y[j] = sum_i expT[j][i] u[i])
    i32x8 Af[8];
    #pragma unroll
    for (int t = 0; t < 8; ++t) {
        #pragma unroll
        for (int d = 0; d < 8; ++d) {
            float v[4];
            #pragma unroll
            for (int y = 0; y < 4; ++y) {
                int sl = 4 * d + y;
                int k  = 16 * (sl & 7) + 4 * g + (sl >> 3);
                int idx = dir ? ((16 * t + m) * L + k) : (k * L + 16 * t + m);
                v[y] = __expf(T[idx]);
            }
            int p01 = pk2_fp8(v[0], v[1]), p23 = pk2_fp8(v[2], v[3]);
            Af[t][d] = (p01 & 0xffff) | (p23 << 16);
        }
    }

    // ---- init state: fwd q0 (emit row 0 + T[START]); bwd u_n (emit row n + T[:,PAD]) ----
    float f1, f2;
    if (dir == 0) {
        f1 = emit[(size_t)b * L + j1]     + T[START_ID * L + j1];
        f2 = emit[(size_t)b * L + j1 + 1] + T[START_ID * L + j1 + 1];
    } else {
        const float* er = emit + ((size_t)n * BATCH + b) * L;
        f1 = er[j1]     + T[j1 * L + PAD_ID];
        f2 = er[j1 + 1] + T[(j1 + 1) * L + PAD_ID];
    }
    float S;
    {
        float mx = fmaxf(f1, f2);
        #pragma unroll
        for (int off = 32; off; off >>= 1) mx = fmaxf(mx, __shfl_xor(mx, off, 64));
        S = mx;
    }
    {
        float p0 = sane(__expf(f1 - S), 1e-9f, 400.f);
        float p1 = sane(__expf(f2 - S), 1e-9f, 400.f);
        int pk = pk2_fp8(p0, p1);
        st[s1]     = (unsigned char)(pk & 0xff);
        st[s1 + 8] = (unsigned char)((pk >> 8) & 0xff);
    }
    asm volatile("s_waitcnt lgkmcnt(0)" ::: "memory");
    i32x4 alo = *(const i32x4*)&st[32 * g];
    i32x4 ahi = *(const i32x4*)&st[32 * g + 16];

    // ---- hot loop: barrier-free, distance-4 emit prefetch ----
    const f32x4 z = {0.f, 0.f, 0.f, 0.f};
    const int base1 = b * L + j1;

    if (steps > 0) {
        auto ldrow = [&](int idx) -> float2 {
            int ii  = idx < steps - 1 ? idx : steps - 1;   // clamp overshoot
            int row = dir ? (n - 1 - ii) : (1 + ii);
            return *(const float2*)(emit + (size_t)row * (BATCH * L) + base1);
        };
        float2 eb0 = ldrow(0), eb1 = ldrow(1), eb2 = ldrow(2), eb3 = ldrow(3);
        int i = 0;

#define MFS(AT) __builtin_amdgcn_mfma_scale_f32_16x16x128_f8f6f4((AT), Aq, z, 0, 0, 0, 127, 0, 127)
#define STEP(EB)                                                               \
        {                                                                      \
            i32x8 Aq;                                                          \
            Aq[0] = alo[0]; Aq[1] = alo[1]; Aq[2] = alo[2]; Aq[3] = alo[3];    \
            Aq[4] = ahi[0]; Aq[5] = ahi[1]; Aq[6] = ahi[2]; Aq[7] = ahi[3];    \
            f32x4 d0 = MFS(Af[0]), d1 = MFS(Af[1]), d2 = MFS(Af[2]),           \
                  d3 = MFS(Af[3]), d4 = MFS(Af[4]), d5 = MFS(Af[5]),           \
                  d6 = MFS(Af[6]), d7 = MFS(Af[7]);                            \
            unsigned int qm = bmax8(__builtin_bit_cast(u32x4, alo),            \
                                    __builtin_bit_cast(u32x4, ahi));           \
            {                                                                  \
                unsigned int q2 = (unsigned int)__shfl_xor((int)qm, 16, 64);   \
                qm = qm > q2 ? qm : q2;                                        \
                q2 = (unsigned int)__shfl_xor((int)qm, 32, 64);                \
                qm = qm > q2 ? qm : q2;                                        \
            }                                                                  \
            float msc = fp8dec(qm);                                            \
            float kk  = frcp(msc);                                             \
            float xe0 = __expf(EB.x) * kk, xe1 = __expf(EB.y) * kk;            \
            const bool sr = (m & 1) != 0, sB = (m & 2) != 0,                   \
                       sC = (m & 4) != 0, sD = (m & 8) != 0;                   \
            float a0 = sr ? d0[2] : d0[0], b0 = sr ? d0[3] : d0[1];            \
            float a1 = sr ? d1[2] : d1[0], b1 = sr ? d1[3] : d1[1];            \
            float a2 = sr ? d2[2] : d2[0], b2 = sr ? d2[3] : d2[1];            \
            float a3 = sr ? d3[2] : d3[0], b3 = sr ? d3[3] : d3[1];            \
            float a4 = sr ? d4[2] : d4[0], b4 = sr ? d4[3] : d4[1];            \
            float a5 = sr ? d5[2] : d5[0], b5 = sr ? d5[3] : d5[1];            \
            float a6 = sr ? d6[2] : d6[0], b6 = sr ? d6[3] : d6[1];            \
            float a7 = sr ? d7[2] : d7[0], b7 = sr ? d7[3] : d7[1];            \
            float aA = sB ? a1 : a0, aB2 = sB ? a3 : a2;                       \
            float aC = sB ? a5 : a4, aD2 = sB ? a7 : a6;                       \
            float bA = sB ? b1 : b0, bB2 = sB ? b3 : b2;                       \
            float bC = sB ? b5 : b4, bD2 = sB ? b7 : b6;                       \
            float aE = sC ? aB2 : aA, aF = sC ? aD2 : aC;                      \
            float bE = sC ? bB2 : bA, bF = sC ? bD2 : bC;                      \
            float c0 = sD ? aF : aE, c1 = sD ? bF : bE;                        \
            float p0 = sane(c0 * xe0, 1e-9f, 400.f);                           \
            float p1 = sane(c1 * xe1, 1e-9f, 400.f);                           \
            int pk = pk2_fp8(p0, p1);                                          \
            st[s1]     = (unsigned char)(pk & 0xff);                           \
            st[s1 + 8] = (unsigned char)((pk >> 8) & 0xff);                    \
            asm volatile("s_waitcnt lgkmcnt(0)" ::: "memory");                 \
            alo = *(const i32x4*)&st[32 * g];                                  \
            ahi = *(const i32x4*)&st[32 * g + 16];                             \
            S += __logf(msc);                                                  \
        }

        for (;;) {
            STEP(eb0); eb0 = ldrow(i + 4); if (++i == steps) break;
            STEP(eb1); eb1 = ldrow(i + 4); if (++i == steps) break;
            STEP(eb2); eb2 = ldrow(i + 4); if (++i == steps) break;
            STEP(eb3); eb3 = ldrow(i + 4); if (++i == steps) break;
        }
#undef STEP
#undef MFS
    }

    // ---- seam + scale to ws (byte order identical to r12: slot s holds j=k(s)) ----
    if (m == 0) {
        i32x4* sp = (i32x4*)(ws + (dir ? WS_QB : WS_QF) + b * L + 32 * g);
        sp[0] = alo; sp[1] = ahi;
    }
    if (lane == 0) {
        ((float*)(ws + (dir ? WS_SB : WS_SF)))[b] = S;
        if (dir == 0) ((int*)(ws + WS_N))[b] = n;
    }
}

// Exact-f32 join: enc_b = Sf + Sb + log(q_kf^T E u_{kf+1})  (n=0: Sf + log(q0.expTpad))
__global__ __launch_bounds__(64, 1) void k_join(
        const float* __restrict__ T, const unsigned char* __restrict__ ws,
        float* __restrict__ out) {
    const int b = blockIdx.x;
    const int lane = threadIdx.x;
    __shared__ float qsh[L], ush[L];

    const int n = ((const int*)(ws + WS_N))[b];
    // decode seam bytes (store-order slot s -> label 16*(s&7)+(s>>3))
    #pragma unroll
    for (int k = 0; k < 2; ++k) {
        int s = lane + 64 * k;
        int j = 16 * (s & 7) + (s >> 3);
        qsh[j] = fp8dec(ws[WS_QF + b * L + s]);
        ush[j] = fp8dec(ws[WS_QB + b * L + s]);
    }
    __syncthreads();

    float ev = 0.f;
    if (n >= 1) {
        #pragma unroll
        for (int k = 0; k < 2; ++k) {
            int j = lane + 64 * k;
            float v = 0.f;
            for (int i = 0; i < L; ++i)
                v = fmaf(qsh[i], __expf(T[i * L + j]), v);
            ev += v * ush[j];
        }
    } else {
        #pragma unroll
        for (int k = 0; k < 2; ++k) {
            int j = lane + 64 * k;
            ev += qsh[j] * __expf(T[j * L + PAD_ID]);
        }
    }
    #pragma unroll
    for (int off = 32; off; off >>= 1) ev += __shfl_xor(ev, off, 64);

    if (lane == 0) {
        float Sf = ((const float*)(ws + WS_SF))[b];
        float Sb = (n >= 1) ? ((const float*)(ws + WS_SB))[b] : 0.f;
        float enc = Sf + Sb + __logf(fmaxf(ev, 1e-35f));
        atomicAdd(out, sane(enc, -1e30f, 1e30f));
    }
}

extern "C" void kernel_launch(void* const* d_in, const int* in_sizes, int n_in,
                              void* d_out, int out_size, void* d_ws, size_t ws_size,
                              hipStream_t stream) {
    const float* emit   = (const float*)d_in[0];
    const int*   labels = (const int*)d_in[1];
    const void*  masks  = d_in[2];
    const float* T      = (const float*)d_in[3];
    float* out = (float*)d_out;
    unsigned char* ws = (unsigned char*)d_ws;

    hipMemsetAsync(d_out, 0, sizeof(float), stream);
    k_scan<<<dim3(3 * BATCH), dim3(64), 0, stream>>>(emit, labels, masks, T, ws, out);
    k_join<<<dim3(BATCH),     dim3(64), 0, stream>>>(T, ws, out);
}